// Round 6
// baseline (8937.789 us; speedup 1.0000x reference)
//
#include <hip/hip_runtime.h>

#define F_IN 16
#define HID 64
#define ITERS 50
#define COST_OFFSET 4.0f

// f64 atomic add via integer CAS — works on any memory type.
__device__ inline void atomic_add_f64(double* addr, double val) {
    unsigned long long* a = (unsigned long long*)addr;
    unsigned long long old = *a;
    while (true) {
        unsigned long long assumed = old;
        double sum = __longlong_as_double(assumed) + val;
        old = atomicCAS(a, assumed, __double_as_longlong(sum));
        if (old == assumed) break;
    }
}

// ---------------- mask dtype detection -------------------------------------
// bool8 mask: sum of first N bytes == 1 (exactly one True).
// int32/f32 mask: first N bytes cover elements [0, N/4) only; sink is at
// N-1, so the sum is 0. flag=1 -> byte mask, flag=0 -> 4-byte mask.
__global__ void detect_kernel(const unsigned char* __restrict__ m, int N,
                              int* __restrict__ flag) {
    __shared__ int s[256];
    int t = threadIdx.x;
    int acc = 0;
    for (int i = t; i < N; i += 256) acc += (m[i] != 0);
    s[t] = acc;
    __syncthreads();
    for (int w = 128; w > 0; w >>= 1) {
        if (t < w) s[t] += s[t + w];
        __syncthreads();
    }
    if (t == 0) *flag = (s[0] == 1) ? 1 : 0;
}

// ---------------- Encoder: per-edge MLP -> logr (out0), r (out2) -----------
__global__ __launch_bounds__(256) void encoder_kernel(
    const float* __restrict__ X,
    const float* __restrict__ W1,
    const float* __restrict__ b1,
    const float* __restrict__ W2,
    const float* __restrict__ b2,
    float* __restrict__ out_logr,    // d_out[0..E) (tail clobbered by z, rewritten later)
    float* __restrict__ out_r,       // d_out[E+N ..): r scratch (f32)
    int E)
{
    int e = blockIdx.x * blockDim.x + threadIdx.x;
    if (e >= E) return;

    float x[F_IN];
    const float4* xv = reinterpret_cast<const float4*>(X + (size_t)e * F_IN);
    #pragma unroll
    for (int i = 0; i < F_IN / 4; ++i) {
        float4 v = xv[i];
        x[4*i+0] = v.x; x[4*i+1] = v.y; x[4*i+2] = v.z; x[4*i+3] = v.w;
    }

    float h[HID];
    #pragma unroll
    for (int j = 0; j < HID; ++j) h[j] = b1[j];

    #pragma unroll
    for (int i = 0; i < F_IN; ++i) {
        float xi = x[i];
        const float* w = W1 + i * HID;
        #pragma unroll
        for (int j = 0; j < HID; ++j) h[j] = fmaf(xi, w[j], h[j]);
    }

    float u = b2[0];
    #pragma unroll
    for (int j = 0; j < HID; ++j) u = fmaf(fmaxf(h[j], 0.0f), W2[j], u);

    float sp = fmaxf(u, 0.0f) + log1pf(expf(-fabsf(u)));   // softplus
    float cost = sp + COST_OFFSET;
    out_logr[e] = -cost;              // log(exp(-cost)) == -cost
    out_r[e]    = expf(-cost);
}

// ---------------- init: bvec = b (f64), z0 = z1 = z2 = b --------------------
__global__ __launch_bounds__(256) void init_kernel(
    const unsigned char* __restrict__ m8,
    const int* __restrict__ m32,
    const int* __restrict__ flag,
    double* __restrict__ bvec,
    double* __restrict__ z0, double* __restrict__ z1, double* __restrict__ z2,
    int N)
{
    int i = blockIdx.x * blockDim.x + threadIdx.x;
    if (i >= N) return;
    double b;
    if (*flag) b = (m8[i]  != 0) ? 1.0 : 0.0;   // bool8 mask
    else       b = (m32[i] != 0) ? 1.0 : 0.0;   // int32 / f32 mask
    bvec[i] = b;
    z0[i] = b; z1[i] = b; z2[i] = b;
}

// ---------------- one value-iteration step (f64, CAS accumulate) -----------
// zout was pre-initialized to b; resets zclr to b for the step after next.
__global__ __launch_bounds__(256) void iter_kernel(
    const int* __restrict__ src,
    const int* __restrict__ dst,
    const float* __restrict__ r,
    const double* __restrict__ zin,
    double* __restrict__ zout,
    double* __restrict__ zclr,
    const double* __restrict__ bvec,
    int E, int N)
{
    int tid = blockIdx.x * blockDim.x + threadIdx.x;
    int stride = gridDim.x * blockDim.x;

    for (int i = tid; i < N; i += stride)
        zclr[i] = bvec[i];

    for (int e = tid; e < E; e += stride) {
        double msg = (double)r[e] * zin[dst[e]];
        if (msg != 0.0) atomic_add_f64(zout + src[e], msg);
    }
}

// ---------------- final1: log z -> out1 ------------------------------------
__global__ __launch_bounds__(256) void final1_kernel(
    const double* __restrict__ z,
    float* __restrict__ out_logz,
    int N)
{
    int i = blockIdx.x * blockDim.x + threadIdx.x;
    if (i < N) out_logz[i] = (float)log(z[i]);
}

// ---------------- final2: probs + rewrite tail logr (z dead now) -----------
__global__ __launch_bounds__(256) void final2_kernel(
    const int* __restrict__ src,
    const int* __restrict__ dst,
    const float* __restrict__ out_logz,
    float* __restrict__ out_logr,    // rewrite only e >= T0 (z-clobbered tail)
    float* probs_r,                  // reads r, writes probs (same slot)
    int E, int T0)
{
    int e = blockIdx.x * blockDim.x + threadIdx.x;
    if (e >= E) return;

    float rr = probs_r[e];
    float p  = rr * expf(out_logz[dst[e]] - out_logz[src[e]]);
    if (e >= T0) out_logr[e] = logf(rr);
    probs_r[e] = p;
}

// ---------------- launch -----------------------------------------------------
extern "C" void kernel_launch(void* const* d_in, const int* in_sizes, int n_in,
                              void* d_out, int out_size, void* d_ws, size_t ws_size,
                              hipStream_t stream)
{
    const int*           edge_index = (const int*)d_in[0];   // [2, E] = [src; dst]
    const float*         X          = (const float*)d_in[1]; // [E, 16]
    const unsigned char* mask8      = (const unsigned char*)d_in[2];
    const int*           mask32     = (const int*)d_in[2];
    const float*         W1         = (const float*)d_in[3];
    const float*         b1         = (const float*)d_in[4];
    const float*         W2         = (const float*)d_in[5];
    const float*         b2         = (const float*)d_in[6];

    const int E = in_sizes[0] / 2;
    const int N = in_sizes[2];
    const int* src = edge_index;
    const int* dst = edge_index + E;

    float* out      = (float*)d_out;
    float* out_logr = out;                       // [E]
    float* out_logz = out + E;                   // [N]
    float* out_pr   = out + (size_t)E + N;       // [E] r scratch, then probs

    // 4 f64 buffers (bvec, z0, z1, z2) in the TAIL of the out_logr region.
    const int Nr     = (N + 63) & ~63;
    const int zslots = 4 * Nr * 2;               // f32 slots
    const int T0     = E - zslots;               // 8B-aligned (Nr mult of 64)
    double* dbase = (double*)(out + T0);
    double* bvec  = dbase;
    double* bufs[3] = { dbase + Nr, dbase + 2 * Nr, dbase + 3 * Nr };

    int* flag = (int*)d_ws;                      // 4 bytes of scratch

    detect_kernel<<<1, 256, 0, stream>>>(mask8, N, flag);
    encoder_kernel<<<(E + 255) / 256, 256, 0, stream>>>(
        X, W1, b1, W2, b2, out_logr, out_pr, E);
    init_kernel<<<(N + 255) / 256, 256, 0, stream>>>(
        mask8, mask32, flag, bvec, bufs[0], bufs[1], bufs[2], N);

    for (int k = 0; k < ITERS; ++k) {
        iter_kernel<<<2048, 256, 0, stream>>>(
            src, dst, out_pr,
            bufs[k % 3], bufs[(k + 1) % 3], bufs[(k + 2) % 3],
            bvec, E, N);
    }

    final1_kernel<<<(N + 255) / 256, 256, 0, stream>>>(
        bufs[ITERS % 3], out_logz, N);
    final2_kernel<<<(E + 255) / 256, 256, 0, stream>>>(
        src, dst, out_logz, out_logr, out_pr, E, T0);
}

// Round 7
// 1357.049 us; speedup vs baseline: 6.5862x; 6.5862x over previous
//
#include <hip/hip_runtime.h>

#define F_IN 16
#define HID 64
#define ITERS 50
#define COST_OFFSET 4.0f
#define SCAN_T 1024

// f64 atomic add via integer CAS — fallback path only.
__device__ inline void atomic_add_f64(double* addr, double val) {
    unsigned long long* a = (unsigned long long*)addr;
    unsigned long long old = *a;
    while (true) {
        unsigned long long assumed = old;
        double sum = __longlong_as_double(assumed) + val;
        old = atomicCAS(a, assumed, __double_as_longlong(sum));
        if (old == assumed) break;
    }
}

// ---------------- mask dtype detection (proved out in round 6) -------------
__global__ void detect_kernel(const unsigned char* __restrict__ m, int N,
                              int* __restrict__ flag) {
    __shared__ int s[256];
    int t = threadIdx.x;
    int acc = 0;
    for (int i = t; i < N; i += 256) acc += (m[i] != 0);
    s[t] = acc;
    __syncthreads();
    for (int w = 128; w > 0; w >>= 1) {
        if (t < w) s[t] += s[t + w];
        __syncthreads();
    }
    if (t == 0) *flag = (s[0] == 1) ? 1 : 0;
}

// ---------------- Encoder: per-edge MLP -> logr (out0), r (out2) -----------
__global__ __launch_bounds__(256) void encoder_kernel(
    const float* __restrict__ X,
    const float* __restrict__ W1,
    const float* __restrict__ b1,
    const float* __restrict__ W2,
    const float* __restrict__ b2,
    float* __restrict__ out_logr,
    float* __restrict__ out_r,
    int E)
{
    int e = blockIdx.x * blockDim.x + threadIdx.x;
    if (e >= E) return;

    float x[F_IN];
    const float4* xv = reinterpret_cast<const float4*>(X + (size_t)e * F_IN);
    #pragma unroll
    for (int i = 0; i < F_IN / 4; ++i) {
        float4 v = xv[i];
        x[4*i+0] = v.x; x[4*i+1] = v.y; x[4*i+2] = v.z; x[4*i+3] = v.w;
    }

    float h[HID];
    #pragma unroll
    for (int j = 0; j < HID; ++j) h[j] = b1[j];

    #pragma unroll
    for (int i = 0; i < F_IN; ++i) {
        float xi = x[i];
        const float* w = W1 + i * HID;
        #pragma unroll
        for (int j = 0; j < HID; ++j) h[j] = fmaf(xi, w[j], h[j]);
    }

    float u = b2[0];
    #pragma unroll
    for (int j = 0; j < HID; ++j) u = fmaf(fmaxf(h[j], 0.0f), W2[j], u);

    float sp = fmaxf(u, 0.0f) + log1pf(expf(-fabsf(u)));   // softplus
    float cost = sp + COST_OFFSET;
    out_logr[e] = -cost;
    out_r[e]    = expf(-cost);
}

// ---------------- CSR build -------------------------------------------------
__global__ __launch_bounds__(256) void zero_kernel(int* __restrict__ p, int n) {
    int i = blockIdx.x * blockDim.x + threadIdx.x;
    if (i < n) p[i] = 0;
}

__global__ __launch_bounds__(256) void hist_kernel(
    const int* __restrict__ src, int* __restrict__ cnt, int E)
{
    int tid = blockIdx.x * blockDim.x + threadIdx.x;
    int stride = gridDim.x * blockDim.x;
    for (int e = tid; e < E; e += stride) atomicAdd(&cnt[src[e]], 1);
}

// single-block exclusive scan, 4 elements/thread (N up to a few hundred K)
__global__ __launch_bounds__(SCAN_T) void scan_kernel(
    const int* __restrict__ cnt, int* __restrict__ row,
    int* __restrict__ ofs, int N)
{
    __shared__ int s[SCAN_T];
    int t = threadIdx.x;
    int running = 0;
    for (int base = 0; base < N; base += SCAN_T * 4) {
        int i0 = base + t * 4;
        int a0 = (i0 + 0 < N) ? cnt[i0 + 0] : 0;
        int a1 = (i0 + 1 < N) ? cnt[i0 + 1] : 0;
        int a2 = (i0 + 2 < N) ? cnt[i0 + 2] : 0;
        int a3 = (i0 + 3 < N) ? cnt[i0 + 3] : 0;
        int tsum = a0 + a1 + a2 + a3;
        s[t] = tsum;
        __syncthreads();
        for (int o = 1; o < SCAN_T; o <<= 1) {
            int x = (t >= o) ? s[t - o] : 0;
            __syncthreads();
            s[t] += x;
            __syncthreads();
        }
        int incl  = s[t];
        int total = s[SCAN_T - 1];
        int e = running + incl - tsum;
        if (i0 + 0 < N) { row[i0 + 0] = e; ofs[i0 + 0] = e; } e += a0;
        if (i0 + 1 < N) { row[i0 + 1] = e; ofs[i0 + 1] = e; } e += a1;
        if (i0 + 2 < N) { row[i0 + 2] = e; ofs[i0 + 2] = e; } e += a2;
        if (i0 + 3 < N) { row[i0 + 3] = e; ofs[i0 + 3] = e; }
        running += total;
        __syncthreads();
    }
    if (t == 0) row[N] = running;
}

__global__ __launch_bounds__(256) void scatter_kernel(
    const int* __restrict__ src, const int* __restrict__ dst,
    const float* __restrict__ r, int* __restrict__ ofs,
    float* __restrict__ csr_r, int* __restrict__ csr_dst, int E)
{
    int tid = blockIdx.x * blockDim.x + threadIdx.x;
    int stride = gridDim.x * blockDim.x;
    for (int e = tid; e < E; e += stride) {
        int p = atomicAdd(&ofs[src[e]], 1);
        csr_r[p]   = r[e];
        csr_dst[p] = dst[e];
    }
}

// ---------------- init b-vector / z0 ----------------------------------------
__global__ __launch_bounds__(256) void initz_kernel(
    const unsigned char* __restrict__ m8, const int* __restrict__ m32,
    const int* __restrict__ flag,
    double* __restrict__ bvec, double* __restrict__ z0, int N)
{
    int i = blockIdx.x * blockDim.x + threadIdx.x;
    if (i >= N) return;
    double b = (*flag) ? ((m8[i] != 0) ? 1.0 : 0.0)
                       : ((m32[i] != 0) ? 1.0 : 0.0);
    bvec[i] = b;
    z0[i]   = b;
}

// ---------------- gather iteration: z_new = b + CSR row-dot -----------------
__global__ __launch_bounds__(256) void gather_kernel(
    const int* __restrict__ row,
    const float* __restrict__ csr_r,
    const int* __restrict__ csr_dst,
    const double* __restrict__ zin,
    double* __restrict__ zout,
    const double* __restrict__ bvec,
    int N)
{
    int i = blockIdx.x * blockDim.x + threadIdx.x;
    if (i >= N) return;
    int beg = row[i], end = row[i + 1];
    double acc = bvec[i];
    for (int k = beg; k < end; ++k)
        acc += (double)csr_r[k] * zin[csr_dst[k]];
    zout[i] = acc;
}

// ---------------- fallback iteration (round-6, atomic scatter) --------------
__global__ __launch_bounds__(256) void iter_kernel(
    const int* __restrict__ src, const int* __restrict__ dst,
    const float* __restrict__ r,
    const double* __restrict__ zin, double* __restrict__ zout,
    double* __restrict__ zclr, const double* __restrict__ bvec,
    int E, int N)
{
    int tid = blockIdx.x * blockDim.x + threadIdx.x;
    int stride = gridDim.x * blockDim.x;
    for (int i = tid; i < N; i += stride) zclr[i] = bvec[i];
    for (int e = tid; e < E; e += stride) {
        double msg = (double)r[e] * zin[dst[e]];
        if (msg != 0.0) atomic_add_f64(zout + src[e], msg);
    }
}

// ---------------- finals ----------------------------------------------------
__global__ __launch_bounds__(256) void final1_kernel(
    const double* __restrict__ z, float* __restrict__ out_logz, int N)
{
    int i = blockIdx.x * blockDim.x + threadIdx.x;
    if (i < N) out_logz[i] = (float)log(z[i]);
}

__global__ __launch_bounds__(256) void final2_kernel(
    const int* __restrict__ src, const int* __restrict__ dst,
    const float* __restrict__ out_logz,
    float* __restrict__ out_logr,    // rewrite only e >= T0 (fallback tail)
    float* probs_r, int E, int T0)
{
    int e = blockIdx.x * blockDim.x + threadIdx.x;
    if (e >= E) return;
    float rr = probs_r[e];
    float p  = rr * expf(out_logz[dst[e]] - out_logz[src[e]]);
    if (e >= T0) out_logr[e] = logf(rr);
    probs_r[e] = p;
}

// ---------------- launch -----------------------------------------------------
extern "C" void kernel_launch(void* const* d_in, const int* in_sizes, int n_in,
                              void* d_out, int out_size, void* d_ws, size_t ws_size,
                              hipStream_t stream)
{
    const int*           edge_index = (const int*)d_in[0];   // [2, E] = [src; dst]
    const float*         X          = (const float*)d_in[1];
    const unsigned char* mask8      = (const unsigned char*)d_in[2];
    const int*           mask32     = (const int*)d_in[2];
    const float*         W1         = (const float*)d_in[3];
    const float*         b1         = (const float*)d_in[4];
    const float*         W2         = (const float*)d_in[5];
    const float*         b2         = (const float*)d_in[6];

    const int E = in_sizes[0] / 2;
    const int N = in_sizes[2];
    const int* src = edge_index;
    const int* dst = edge_index + E;

    float* out      = (float*)d_out;
    float* out_logr = out;
    float* out_logz = out + E;
    float* out_pr   = out + (size_t)E + N;       // r scratch, then probs

    // --- workspace carve-out (fast path) ---
    char* ws = (char*)d_ws;
    size_t off = 0;
    auto alloc = [&](size_t bytes) -> char* {
        char* p = ws + off;
        off = (off + bytes + 255) & ~(size_t)255;
        return p;
    };
    int*    flag    = (int*)   alloc(4);
    int*    cnt     = (int*)   alloc((size_t)N * 4);
    int*    ofs     = (int*)   alloc((size_t)N * 4);
    int*    row     = (int*)   alloc(((size_t)N + 1) * 4);
    float*  csr_r   = (float*) alloc((size_t)E * 4);
    int*    csr_dst = (int*)   alloc((size_t)E * 4);
    double* bvec    = (double*)alloc((size_t)N * 8);
    double* z0      = (double*)alloc((size_t)N * 8);
    double* z1      = (double*)alloc((size_t)N * 8);
    const bool fast = (off <= ws_size);

    detect_kernel<<<1, 256, 0, stream>>>(mask8, N, flag);
    encoder_kernel<<<(E + 255) / 256, 256, 0, stream>>>(
        X, W1, b1, W2, b2, out_logr, out_pr, E);

    if (fast) {
        // ---- CSR build (one-time) ----
        zero_kernel<<<(N + 255) / 256, 256, 0, stream>>>(cnt, N);
        hist_kernel<<<2048, 256, 0, stream>>>(src, cnt, E);
        scan_kernel<<<1, SCAN_T, 0, stream>>>(cnt, row, ofs, N);
        scatter_kernel<<<2048, 256, 0, stream>>>(
            src, dst, out_pr, ofs, csr_r, csr_dst, E);
        initz_kernel<<<(N + 255) / 256, 256, 0, stream>>>(
            mask8, mask32, flag, bvec, z0, N);

        // ---- 50 atomic-free gather iterations, ping-pong ----
        double* zb[2] = { z0, z1 };
        for (int k = 0; k < ITERS; ++k) {
            gather_kernel<<<(N + 255) / 256, 256, 0, stream>>>(
                row, csr_r, csr_dst, zb[k & 1], zb[(k + 1) & 1], bvec, N);
        }

        final1_kernel<<<(N + 255) / 256, 256, 0, stream>>>(
            zb[ITERS & 1], out_logz, N);
        final2_kernel<<<(E + 255) / 256, 256, 0, stream>>>(
            src, dst, out_logz, out_logr, out_pr, E, /*T0=*/E);
    } else {
        // ---- fallback: round-6 proven path, z buffers in out0 tail ----
        const int Nr     = (N + 63) & ~63;
        const int zslots = 4 * Nr * 2;
        const int T0     = E - zslots;
        double* dbase = (double*)(out + T0);
        double* bv    = dbase;
        double* bufs[3] = { dbase + Nr, dbase + 2 * Nr, dbase + 3 * Nr };

        initz_kernel<<<(N + 255) / 256, 256, 0, stream>>>(
            mask8, mask32, flag, bv, bufs[0], N);
        initz_kernel<<<(N + 255) / 256, 256, 0, stream>>>(
            mask8, mask32, flag, bv, bufs[1], N);
        initz_kernel<<<(N + 255) / 256, 256, 0, stream>>>(
            mask8, mask32, flag, bv, bufs[2], N);

        for (int k = 0; k < ITERS; ++k) {
            iter_kernel<<<2048, 256, 0, stream>>>(
                src, dst, out_pr,
                bufs[k % 3], bufs[(k + 1) % 3], bufs[(k + 2) % 3],
                bv, E, N);
        }

        final1_kernel<<<(N + 255) / 256, 256, 0, stream>>>(
            bufs[ITERS % 3], out_logz, N);
        final2_kernel<<<(E + 255) / 256, 256, 0, stream>>>(
            src, dst, out_logz, out_logr, out_pr, E, T0);
    }
}

// Round 8
// 1023.457 us; speedup vs baseline: 8.7329x; 1.3259x over previous
//
#include <hip/hip_runtime.h>

#define F_IN 16
#define HID 64
#define ITERS 50
#define COST_OFFSET 4.0f
#define SCAN_T 1024

struct __align__(8) Rec { float r; int dst; };

// f64 atomic add via integer CAS — fallback path only.
__device__ inline void atomic_add_f64(double* addr, double val) {
    unsigned long long* a = (unsigned long long*)addr;
    unsigned long long old = *a;
    while (true) {
        unsigned long long assumed = old;
        double sum = __longlong_as_double(assumed) + val;
        old = atomicCAS(a, assumed, __double_as_longlong(sum));
        if (old == assumed) break;
    }
}

// ---------------- mask dtype detection (proved out in round 6) -------------
__global__ void detect_kernel(const unsigned char* __restrict__ m, int N,
                              int* __restrict__ flag) {
    __shared__ int s[256];
    int t = threadIdx.x;
    int acc = 0;
    for (int i = t; i < N; i += 256) acc += (m[i] != 0);
    s[t] = acc;
    __syncthreads();
    for (int w = 128; w > 0; w >>= 1) {
        if (t < w) s[t] += s[t + w];
        __syncthreads();
    }
    if (t == 0) *flag = (s[0] == 1) ? 1 : 0;
}

// ---------------- Encoder: per-edge MLP -> logr (out0), r (out2) -----------
__global__ __launch_bounds__(256) void encoder_kernel(
    const float* __restrict__ X,
    const float* __restrict__ W1,
    const float* __restrict__ b1,
    const float* __restrict__ W2,
    const float* __restrict__ b2,
    float* __restrict__ out_logr,
    float* __restrict__ out_r,
    int E)
{
    int e = blockIdx.x * blockDim.x + threadIdx.x;
    if (e >= E) return;

    float x[F_IN];
    const float4* xv = reinterpret_cast<const float4*>(X + (size_t)e * F_IN);
    #pragma unroll
    for (int i = 0; i < F_IN / 4; ++i) {
        float4 v = xv[i];
        x[4*i+0] = v.x; x[4*i+1] = v.y; x[4*i+2] = v.z; x[4*i+3] = v.w;
    }

    float h[HID];
    #pragma unroll
    for (int j = 0; j < HID; ++j) h[j] = b1[j];

    #pragma unroll
    for (int i = 0; i < F_IN; ++i) {
        float xi = x[i];
        const float* w = W1 + i * HID;
        #pragma unroll
        for (int j = 0; j < HID; ++j) h[j] = fmaf(xi, w[j], h[j]);
    }

    float u = b2[0];
    #pragma unroll
    for (int j = 0; j < HID; ++j) u = fmaf(fmaxf(h[j], 0.0f), W2[j], u);

    float sp = fmaxf(u, 0.0f) + log1pf(expf(-fabsf(u)));   // softplus
    float cost = sp + COST_OFFSET;
    out_logr[e] = -cost;
    out_r[e]    = expf(-cost);
}

// ---------------- CSR build -------------------------------------------------
__global__ __launch_bounds__(256) void zero_kernel(int* __restrict__ p, int n) {
    int i = blockIdx.x * blockDim.x + threadIdx.x;
    if (i < n) p[i] = 0;
}

__global__ __launch_bounds__(256) void hist_kernel(
    const int* __restrict__ src, int* __restrict__ cnt, int E)
{
    int tid = blockIdx.x * blockDim.x + threadIdx.x;
    int stride = gridDim.x * blockDim.x;
    for (int e = tid; e < E; e += stride) atomicAdd(&cnt[src[e]], 1);
}

// single-block exclusive scan, 4 elements/thread — PROVEN in round 7
__global__ __launch_bounds__(SCAN_T) void scan_kernel(
    const int* __restrict__ cnt, int* __restrict__ row,
    int* __restrict__ ofs, int N)
{
    __shared__ int s[SCAN_T];
    int t = threadIdx.x;
    int running = 0;
    for (int base = 0; base < N; base += SCAN_T * 4) {
        int i0 = base + t * 4;
        int a0 = (i0 + 0 < N) ? cnt[i0 + 0] : 0;
        int a1 = (i0 + 1 < N) ? cnt[i0 + 1] : 0;
        int a2 = (i0 + 2 < N) ? cnt[i0 + 2] : 0;
        int a3 = (i0 + 3 < N) ? cnt[i0 + 3] : 0;
        int tsum = a0 + a1 + a2 + a3;
        s[t] = tsum;
        __syncthreads();
        for (int o = 1; o < SCAN_T; o <<= 1) {
            int x = (t >= o) ? s[t - o] : 0;
            __syncthreads();
            s[t] += x;
            __syncthreads();
        }
        int incl  = s[t];
        int total = s[SCAN_T - 1];
        int e = running + incl - tsum;
        if (i0 + 0 < N) { row[i0 + 0] = e; ofs[i0 + 0] = e; } e += a0;
        if (i0 + 1 < N) { row[i0 + 1] = e; ofs[i0 + 1] = e; } e += a1;
        if (i0 + 2 < N) { row[i0 + 2] = e; ofs[i0 + 2] = e; } e += a2;
        if (i0 + 3 < N) { row[i0 + 3] = e; ofs[i0 + 3] = e; }
        running += total;
        __syncthreads();
    }
    if (t == 0) row[N] = running;
}

// scatter into interleaved 8B records — ONE random line per edge
__global__ __launch_bounds__(256) void scatter_kernel(
    const int* __restrict__ src, const int* __restrict__ dst,
    const float* __restrict__ r, int* __restrict__ ofs,
    Rec* __restrict__ recs, int E)
{
    int tid = blockIdx.x * blockDim.x + threadIdx.x;
    int stride = gridDim.x * blockDim.x;
    for (int e = tid; e < E; e += stride) {
        int p = atomicAdd(&ofs[src[e]], 1);
        Rec rc; rc.r = r[e]; rc.dst = dst[e];
        recs[p] = rc;
    }
}

// ---------------- init b-vector / z0 ----------------------------------------
__global__ __launch_bounds__(256) void initz_kernel(
    const unsigned char* __restrict__ m8, const int* __restrict__ m32,
    const int* __restrict__ flag,
    double* __restrict__ bvec, double* __restrict__ z0, int N)
{
    int i = blockIdx.x * blockDim.x + threadIdx.x;
    if (i >= N) return;
    double b = (*flag) ? ((m8[i] != 0) ? 1.0 : 0.0)
                       : ((m32[i] != 0) ? 1.0 : 0.0);
    bvec[i] = b;
    z0[i]   = b;
}

// ---------------- gather iteration: 4 lanes per node ------------------------
__global__ __launch_bounds__(256) void gather_kernel(
    const int* __restrict__ row,
    const Rec* __restrict__ recs,
    const double* __restrict__ zin,
    double* __restrict__ zout,
    const double* __restrict__ bvec,
    int N)
{
    int g = blockIdx.x * blockDim.x + threadIdx.x;
    int node = g >> 2;
    int sub  = g & 3;
    if (node >= N) return;

    int beg = row[node], end = row[node + 1];
    double acc = 0.0;
    for (int k = beg + sub; k < end; k += 4) {
        Rec rc = recs[k];                       // one dwordx2, 4 lanes = 32B
        acc += (double)rc.r * zin[rc.dst];
    }
    acc += __shfl_down(acc, 2, 4);
    acc += __shfl_down(acc, 1, 4);
    if (sub == 0) zout[node] = bvec[node] + acc;
}

// ---------------- fallback iteration (round-6, atomic scatter) --------------
__global__ __launch_bounds__(256) void iter_kernel(
    const int* __restrict__ src, const int* __restrict__ dst,
    const float* __restrict__ r,
    const double* __restrict__ zin, double* __restrict__ zout,
    double* __restrict__ zclr, const double* __restrict__ bvec,
    int E, int N)
{
    int tid = blockIdx.x * blockDim.x + threadIdx.x;
    int stride = gridDim.x * blockDim.x;
    for (int i = tid; i < N; i += stride) zclr[i] = bvec[i];
    for (int e = tid; e < E; e += stride) {
        double msg = (double)r[e] * zin[dst[e]];
        if (msg != 0.0) atomic_add_f64(zout + src[e], msg);
    }
}

// ---------------- finals ----------------------------------------------------
__global__ __launch_bounds__(256) void final1_kernel(
    const double* __restrict__ z, float* __restrict__ out_logz, int N)
{
    int i = blockIdx.x * blockDim.x + threadIdx.x;
    if (i < N) out_logz[i] = (float)log(z[i]);
}

__global__ __launch_bounds__(256) void final2_kernel(
    const int* __restrict__ src, const int* __restrict__ dst,
    const float* __restrict__ out_logz,
    float* __restrict__ out_logr,    // rewrite only e >= T0 (fallback tail)
    float* probs_r, int E, int T0)
{
    int e = blockIdx.x * blockDim.x + threadIdx.x;
    if (e >= E) return;
    float rr = probs_r[e];
    float p  = rr * expf(out_logz[dst[e]] - out_logz[src[e]]);
    if (e >= T0) out_logr[e] = logf(rr);
    probs_r[e] = p;
}

// ---------------- launch -----------------------------------------------------
extern "C" void kernel_launch(void* const* d_in, const int* in_sizes, int n_in,
                              void* d_out, int out_size, void* d_ws, size_t ws_size,
                              hipStream_t stream)
{
    const int*           edge_index = (const int*)d_in[0];   // [2, E] = [src; dst]
    const float*         X          = (const float*)d_in[1];
    const unsigned char* mask8      = (const unsigned char*)d_in[2];
    const int*           mask32     = (const int*)d_in[2];
    const float*         W1         = (const float*)d_in[3];
    const float*         b1         = (const float*)d_in[4];
    const float*         W2         = (const float*)d_in[5];
    const float*         b2         = (const float*)d_in[6];

    const int E = in_sizes[0] / 2;
    const int N = in_sizes[2];
    const int* src = edge_index;
    const int* dst = edge_index + E;

    float* out      = (float*)d_out;
    float* out_logr = out;
    float* out_logz = out + E;
    float* out_pr   = out + (size_t)E + N;       // r scratch, then probs

    // --- workspace carve-out (fast path) ---
    char* ws = (char*)d_ws;
    size_t off = 0;
    auto alloc = [&](size_t bytes) -> char* {
        char* p = ws + off;
        off = (off + bytes + 255) & ~(size_t)255;
        return p;
    };
    int*    flag = (int*)   alloc(4);
    int*    cnt  = (int*)   alloc((size_t)N * 4);
    int*    ofs  = (int*)   alloc((size_t)N * 4);
    int*    row  = (int*)   alloc(((size_t)N + 1) * 4);
    Rec*    recs = (Rec*)   alloc((size_t)E * 8);
    double* bvec = (double*)alloc((size_t)N * 8);
    double* z0   = (double*)alloc((size_t)N * 8);
    double* z1   = (double*)alloc((size_t)N * 8);
    const bool fast = (off <= ws_size);

    detect_kernel<<<1, 256, 0, stream>>>(mask8, N, flag);
    encoder_kernel<<<(E + 255) / 256, 256, 0, stream>>>(
        X, W1, b1, W2, b2, out_logr, out_pr, E);

    if (fast) {
        // ---- CSR build (one-time) ----
        zero_kernel<<<(N + 255) / 256, 256, 0, stream>>>(cnt, N);
        hist_kernel<<<2048, 256, 0, stream>>>(src, cnt, E);
        scan_kernel<<<1, SCAN_T, 0, stream>>>(cnt, row, ofs, N);
        scatter_kernel<<<2048, 256, 0, stream>>>(
            src, dst, out_pr, ofs, recs, E);
        initz_kernel<<<(N + 255) / 256, 256, 0, stream>>>(
            mask8, mask32, flag, bvec, z0, N);

        // ---- 50 atomic-free gather iterations, ping-pong ----
        double* zb[2] = { z0, z1 };
        const int ggrid = (int)(((size_t)4 * N + 255) / 256);
        for (int k = 0; k < ITERS; ++k) {
            gather_kernel<<<ggrid, 256, 0, stream>>>(
                row, recs, zb[k & 1], zb[(k + 1) & 1], bvec, N);
        }

        final1_kernel<<<(N + 255) / 256, 256, 0, stream>>>(
            zb[ITERS & 1], out_logz, N);
        final2_kernel<<<(E + 255) / 256, 256, 0, stream>>>(
            src, dst, out_logz, out_logr, out_pr, E, /*T0=*/E);
    } else {
        // ---- fallback: round-6 proven path, z buffers in out0 tail ----
        const int Nr     = (N + 63) & ~63;
        const int zslots = 4 * Nr * 2;
        const int T0     = E - zslots;
        double* dbase = (double*)(out + T0);
        double* bv    = dbase;
        double* bufs[3] = { dbase + Nr, dbase + 2 * Nr, dbase + 3 * Nr };

        initz_kernel<<<(N + 255) / 256, 256, 0, stream>>>(
            mask8, mask32, flag, bv, bufs[0], N);
        initz_kernel<<<(N + 255) / 256, 256, 0, stream>>>(
            mask8, mask32, flag, bv, bufs[1], N);
        initz_kernel<<<(N + 255) / 256, 256, 0, stream>>>(
            mask8, mask32, flag, bv, bufs[2], N);

        for (int k = 0; k < ITERS; ++k) {
            iter_kernel<<<2048, 256, 0, stream>>>(
                src, dst, out_pr,
                bufs[k % 3], bufs[(k + 1) % 3], bufs[(k + 2) % 3],
                bv, E, N);
        }

        final1_kernel<<<(N + 255) / 256, 256, 0, stream>>>(
            bufs[ITERS % 3], out_logz, N);
        final2_kernel<<<(E + 255) / 256, 256, 0, stream>>>(
            src, dst, out_logz, out_logr, out_pr, E, T0);
    }
}